// Round 1
// baseline (19588.405 us; speedup 1.0000x reference)
//
#include <hip/hip_runtime.h>

#define NS 4096   // sentences
#define DI 1024   // D_IN
#define HH 1024   // HID
#define NB 256    // persistent blocks
#define TPB 256

#define LOG2E 1.4426950408889634f

__device__ __forceinline__ float ld_b(const float* p){
  return __hip_atomic_load(p, __ATOMIC_RELAXED, __HIP_MEMORY_SCOPE_AGENT);
}
__device__ __forceinline__ void st_b(float* p, float v){
  __hip_atomic_store(p, v, __ATOMIC_RELAXED, __HIP_MEMORY_SCOPE_AGENT);
}
__device__ __forceinline__ float fexp2f_(float x){ return __builtin_amdgcn_exp2f(x); }
__device__ __forceinline__ float frcpf_(float x){ return __builtin_amdgcn_rcpf(x); }
// tanh(x) = 1 - 2/(exp(2x)+1); exp(2x)->inf saturates correctly, no branch
__device__ __forceinline__ float ftanh_(float x){ float t = fexp2f_(x*(2.0f*LOG2E)); return 1.0f - 2.0f*frcpf_(t+1.0f); }
__device__ __forceinline__ float fsigm_(float x){ return frcpf_(1.0f + fexp2f_(-x*LOG2E)); }
__device__ __forceinline__ float fexpf_(float x){ return fexp2f_(x*LOG2E); }

// ---------------- grid barrier (persistent kernel, 256 blocks) ----------------
// __syncthreads() drains each wave's vmem (compiler emits vmcnt(0) before
// s_barrier), so all bypass stores of the block are globally visible before
// thread 0 arrives.
__device__ void gbar(int* cnt, int* gen){
  __syncthreads();
  if (threadIdx.x == 0){
    asm volatile("s_waitcnt vmcnt(0) lgkmcnt(0)" ::: "memory");
    int g = __hip_atomic_load(gen, __ATOMIC_RELAXED, __HIP_MEMORY_SCOPE_AGENT);
    int prev = __hip_atomic_fetch_add(cnt, 1, __ATOMIC_RELAXED, __HIP_MEMORY_SCOPE_AGENT);
    if (prev == NB-1){
      __hip_atomic_store(cnt, 0, __ATOMIC_RELAXED, __HIP_MEMORY_SCOPE_AGENT);
      asm volatile("s_waitcnt vmcnt(0)" ::: "memory");   // cnt reset lands before release
      __hip_atomic_store(gen, g+1, __ATOMIC_RELAXED, __HIP_MEMORY_SCOPE_AGENT);
    } else {
      while (__hip_atomic_load(gen, __ATOMIC_RELAXED, __HIP_MEMORY_SCOPE_AGENT) == g)
        __builtin_amdgcn_s_sleep(1);
    }
  }
  __syncthreads();
}

// ---------------- precompute kernels ----------------
__global__ void initk(int* bar){ if (threadIdx.x < 64) bar[threadIdx.x] = 0; }

// C[M,N] = A[M,K] @ B[K,N]; TR: store C^T [N,M] instead (for HQT/HAT)
template<bool TR>
__global__ __launch_bounds__(256) void gemmk(const float* __restrict__ A,
                                             const float* __restrict__ B,
                                             float* __restrict__ C,
                                             int M, int N, int K)
{
  __shared__ float As[64][17];
  __shared__ float Bs[16][68];
  const int tid = threadIdx.x;
  const int tx = tid & 15, ty = tid >> 4;
  const int r0 = blockIdx.y*64, c0 = blockIdx.x*64;
  float acc[4][4] = {};
  for (int k0 = 0; k0 < K; k0 += 16){
    int ar = tid >> 2, aq = tid & 3;
    float4 a4 = *(const float4*)&A[(size_t)(r0+ar)*K + k0 + aq*4];
    As[ar][aq*4+0]=a4.x; As[ar][aq*4+1]=a4.y; As[ar][aq*4+2]=a4.z; As[ar][aq*4+3]=a4.w;
    int br = tid >> 4, bq = tid & 15;
    float4 b4 = *(const float4*)&B[(size_t)(k0+br)*N + c0 + bq*4];
    Bs[br][bq*4+0]=b4.x; Bs[br][bq*4+1]=b4.y; Bs[br][bq*4+2]=b4.z; Bs[br][bq*4+3]=b4.w;
    __syncthreads();
    #pragma unroll
    for (int kk=0; kk<16; ++kk){
      float a0=As[ty*4+0][kk], a1=As[ty*4+1][kk], a2=As[ty*4+2][kk], a3=As[ty*4+3][kk];
      float b0=Bs[kk][tx*4+0], b1=Bs[kk][tx*4+1], b2=Bs[kk][tx*4+2], b3=Bs[kk][tx*4+3];
      acc[0][0]+=a0*b0; acc[0][1]+=a0*b1; acc[0][2]+=a0*b2; acc[0][3]+=a0*b3;
      acc[1][0]+=a1*b0; acc[1][1]+=a1*b1; acc[1][2]+=a1*b2; acc[1][3]+=a1*b3;
      acc[2][0]+=a2*b0; acc[2][1]+=a2*b1; acc[2][2]+=a2*b2; acc[2][3]+=a2*b3;
      acc[3][0]+=a3*b0; acc[3][1]+=a3*b1; acc[3][2]+=a3*b2; acc[3][3]+=a3*b3;
    }
    __syncthreads();
  }
  if constexpr (!TR){
    #pragma unroll
    for (int i=0;i<4;++i){
      float4 o; o.x=acc[i][0]; o.y=acc[i][1]; o.z=acc[i][2]; o.w=acc[i][3];
      *(float4*)&C[(size_t)(r0+ty*4+i)*N + c0 + tx*4] = o;
    }
  } else {
    __shared__ float Cs[64][65];
    #pragma unroll
    for (int i=0;i<4;++i)
      #pragma unroll
      for (int j=0;j<4;++j) Cs[ty*4+i][tx*4+j] = acc[i][j];
    __syncthreads();
    #pragma unroll
    for (int e=0;e<16;++e){
      int idx = tid + 256*e;
      int cc = idx >> 6, rr = idx & 63;
      C[(size_t)(c0+cc)*M + r0 + rr] = Cs[rr][cc];
    }
  }
}

__global__ void transpk(const float* __restrict__ in, float* __restrict__ out, int R, int C){
  __shared__ float s[32][33];
  int c0 = blockIdx.x*32, r0 = blockIdx.y*32;
  int x = threadIdx.x, y = threadIdx.y;
  for (int i=0;i<32;i+=8) s[y+i][x] = in[(size_t)(r0+y+i)*C + c0 + x];
  __syncthreads();
  for (int i=0;i<32;i+=8) out[(size_t)(c0+y+i)*R + r0 + x] = s[x][y+i];
}

// Ms[n] = mem[n] . score_w
__global__ void msk(const float* __restrict__ mem, const float* __restrict__ sw, float* __restrict__ Ms){
  int wv = threadIdx.x >> 6, ln = threadIdx.x & 63;
  int n = blockIdx.x*4 + wv;
  const float* row = &mem[(size_t)n*DI];
  float acc = 0.f;
  #pragma unroll 4
  for (int m=0;m<16;++m){ int idx = ln + (m<<6); acc += row[idx]*sw[idx]; }
  #pragma unroll
  for (int off=32; off; off>>=1) acc += __shfl_xor(acc, off, 64);
  if (ln==0) Ms[n] = acc;
}

// ---------------- persistent step kernel phases ----------------
// attention score pass: block owns 16 rows; e_n = tanh(F[n]+qw).v -> w_n=exp(e)
__device__ __forceinline__ void att_phase(const float* __restrict__ F, const float* vlds,
                                          const float* qwsrc, float* wout, float* spart,
                                          int bb, int tid, float* qw_lds, float* wred)
{
  #pragma unroll
  for (int i=0;i<4;++i) qw_lds[tid*4+i] = ld_b(&qwsrc[tid*4+i]);
  __syncthreads();
  int r = tid >> 4, ll = tid & 15;
  int n = 16*bb + r;
  const float* Fr = &F[(size_t)n*HH];
  float e = 0.f;
  #pragma unroll
  for (int m=0;m<16;++m){
    int idx = (ll<<2) + (m<<6);
    float4 f = *(const float4*)&Fr[idx];
    float4 q = *(const float4*)&qw_lds[idx];
    float4 v = *(const float4*)&vlds[idx];
    e += ftanh_(f.x+q.x)*v.x;
    e += ftanh_(f.y+q.y)*v.y;
    e += ftanh_(f.z+q.z)*v.z;
    e += ftanh_(f.w+q.w)*v.w;
  }
  #pragma unroll
  for (int off=8; off; off>>=1) e += __shfl_xor(e, off, 16);
  float w = fexpf_(e);                    // |e| <= sum|v| ~ 45: no overflow possible
  if (ll==0){ st_b(&wout[n], w); wred[r] = w; }
  __syncthreads();
  if (tid==0){
    float s = 0.f;
    #pragma unroll
    for (int r2=0;r2<16;++r2) s += wred[r2];
    st_b(&spart[bb], s);
  }
}

// column pass: outv[j] = (sum_n win[n]*MT[j][n]) / (sum spart)  for block's 4 j's
__device__ __forceinline__ void col_phase(const float* __restrict__ MT, const float* win,
                                          const float* spart, float* outv,
                                          int bb, int wv, int ln)
{
  float sp = 0.f;
  #pragma unroll
  for (int m=0;m<4;++m) sp += ld_b(&spart[ln + (m<<6)]);
  #pragma unroll
  for (int off=32; off; off>>=1) sp += __shfl_xor(sp, off, 64);
  int j = 4*bb + wv;
  const float* row = &MT[(size_t)j*NS];
  float acc = 0.f;
  #pragma unroll 4
  for (int m=0;m<64;++m){
    int idx = ln + (m<<6);
    acc += row[idx] * ld_b(&win[idx]);
  }
  #pragma unroll
  for (int off=32; off; off>>=1) acc += __shfl_xor(acc, off, 64);
  if (ln==0) st_b(&outv[j], acc/sp);
}

__global__ __launch_bounds__(TPB) void stepk(
  const float* __restrict__ attn_feat, const float* __restrict__ hop_feat,
  const float* __restrict__ HQT, const float* __restrict__ HAT,
  const float* __restrict__ memT, const float* __restrict__ wqT,
  const float* __restrict__ Ms,
  float* xst, float* hb, float* qw1, float* qw2, float* qw3,
  float* w1, float* w2, float* w3, float* s1p, float* s2p, float* s3p,
  int* bar,
  const float* __restrict__ hop_v, const float* __restrict__ attn_v,
  const float* __restrict__ init_h, const float* __restrict__ init_c,
  const float* __restrict__ init_i,
  const float* __restrict__ w_ih, const float* __restrict__ w_hh,
  const float* __restrict__ b_ih, const float* __restrict__ b_hh,
  const float* __restrict__ score_b, const int* __restrict__ n_step,
  float* __restrict__ out)
{
  const int bb = blockIdx.x;
  const int tid = threadIdx.x;
  const int wv = tid >> 6, ln = tid & 63;
  __shared__ float x_lds[DI], h_lds[HH], qw_lds[HH];
  __shared__ float vhop[HH], vatt[HH];
  __shared__ float gbuf[16], wred[16], c_lds[4];
  int* cnt = bar; int* gen = bar + 32;

  *(float4*)&vhop[tid*4] = *(const float4*)&hop_v[tid*4];
  *(float4*)&vatt[tid*4] = *(const float4*)&attn_v[tid*4];
  const int T = *n_step;
  const float sb = score_b[0];

  for (int t = 0; t < T; ++t){
    const int hw = (t+1) & 1;
    // ---- Ph1: LSTM cell (block owns h/c dims 4bb..4bb+3 -> 16 gate rows) ----
    if (t == 0){
      *(float4*)&x_lds[tid*4] = *(const float4*)&init_i[tid*4];
      *(float4*)&h_lds[tid*4] = *(const float4*)&init_h[tid*4];
    } else {
      const float* hsrc = hb + (size_t)(t&1)*HH;
      #pragma unroll
      for (int i=0;i<4;++i){
        x_lds[tid*4+i] = ld_b(&xst[tid*4+i]);
        h_lds[tid*4+i] = ld_b(&hsrc[tid*4+i]);
      }
    }
    __syncthreads();
    {
      int grp = tid >> 4, ll = tid & 15;
      int gate = grp >> 2, d = grp & 3;
      int R = gate*HH + 4*bb + d;
      const float4* wi = (const float4*)&w_ih[(size_t)R*DI];
      const float4* wh = (const float4*)&w_hh[(size_t)R*HH];
      const float4* xl = (const float4*)x_lds;
      const float4* hl = (const float4*)h_lds;
      float p = 0.f;
      #pragma unroll
      for (int m=0;m<16;++m){
        int i4 = ll + (m<<4);
        float4 a = wi[i4], x = xl[i4];
        p += a.x*x.x + a.y*x.y + a.z*x.z + a.w*x.w;
        float4 b = wh[i4], h = hl[i4];
        p += b.x*h.x + b.y*h.y + b.z*h.z + b.w*h.w;
      }
      #pragma unroll
      for (int off=8; off; off>>=1) p += __shfl_xor(p, off, 16);
      if (ll == 0) gbuf[grp] = p + b_ih[R] + b_hh[R];
    }
    __syncthreads();
    if (tid < 4){
      float ii = fsigm_(gbuf[tid]);
      float ff = fsigm_(gbuf[4+tid]);
      float gg = ftanh_(gbuf[8+tid]);
      float oo = fsigm_(gbuf[12+tid]);
      float c  = (t==0) ? init_c[4*bb+tid] : c_lds[tid];
      float c2 = ff*c + ii*gg;
      c_lds[tid] = c2;
      st_b(&hb[(size_t)hw*HH + 4*bb + tid], oo*ftanh_(c2));
    }
    gbar(cnt, gen);

    // ---- Ph2: qw1 = h @ hop_wq (block's 4 columns via wqT rows) ----
    {
      const float* hsrc = hb + (size_t)hw*HH;
      int j = 4*bb + wv;
      const float* row = &wqT[(size_t)j*HH];
      float acc = 0.f;
      #pragma unroll 4
      for (int m=0;m<16;++m){
        int idx = ln + (m<<6);
        acc += row[idx] * ld_b(&hsrc[idx]);
      }
      #pragma unroll
      for (int off=32; off; off>>=1) acc += __shfl_xor(acc, off, 64);
      if (ln == 0) st_b(&qw1[j], acc);
    }
    gbar(cnt, gen);

    // ---- Ph3: hop attention 1 ----
    att_phase(hop_feat, vhop, qw1, w1, s1p, bb, tid, qw_lds, wred);
    gbar(cnt, gen);
    // ---- Ph4: qw2 = (w1 @ HQ)/s1 ----
    col_phase(HQT, w1, s1p, qw2, bb, wv, ln);
    gbar(cnt, gen);
    // ---- Ph5: hop attention 2 ----
    att_phase(hop_feat, vhop, qw2, w2, s2p, bb, tid, qw_lds, wred);
    gbar(cnt, gen);
    // ---- Ph6: qw3 = (w2 @ HA)/s2 ----
    col_phase(HAT, w2, s2p, qw3, bb, wv, ln);
    gbar(cnt, gen);
    // ---- Ph7: final attention ----
    att_phase(attn_feat, vatt, qw3, w3, s3p, bb, tid, qw_lds, wred);
    gbar(cnt, gen);
    // ---- Ph8: x = (w3 @ mem)/s3 ; score ----
    col_phase(memT, w3, s3p, xst, bb, wv, ln);
    if (bb == 0 && wv == 0){
      float sp = 0.f;
      #pragma unroll
      for (int m=0;m<4;++m) sp += ld_b(&s3p[ln + (m<<6)]);
      #pragma unroll
      for (int off=32; off; off>>=1) sp += __shfl_xor(sp, off, 64);
      float sd = 0.f;
      #pragma unroll 4
      for (int m=0;m<64;++m){
        int idx = ln + (m<<6);
        sd += Ms[idx] * ld_b(&w3[idx]);
      }
      #pragma unroll
      for (int off=32; off; off>>=1) sd += __shfl_xor(sd, off, 64);
      if (ln == 0) out[t] = sd/sp + sb;
    }
    gbar(cnt, gen);
  }
}

// ---------------- host launch ----------------
extern "C" void kernel_launch(void* const* d_in, const int* in_sizes, int n_in,
                              void* d_out, int out_size, void* d_ws, size_t ws_size,
                              hipStream_t stream)
{
  (void)in_sizes; (void)n_in; (void)out_size;
  const float* attn_mem = (const float*)d_in[0];
  const float* attn_wm  = (const float*)d_in[1];
  const float* attn_wq  = (const float*)d_in[2];
  const float* attn_v   = (const float*)d_in[3];
  const float* hop_wm   = (const float*)d_in[4];
  const float* hop_wq   = (const float*)d_in[5];
  const float* hop_v    = (const float*)d_in[6];
  const float* init_h   = (const float*)d_in[7];
  const float* init_c   = (const float*)d_in[8];
  const float* init_i   = (const float*)d_in[9];
  const float* w_ih     = (const float*)d_in[10];
  const float* w_hh     = (const float*)d_in[11];
  const float* b_ih     = (const float*)d_in[12];
  const float* b_hh     = (const float*)d_in[13];
  const float* score_w  = (const float*)d_in[14];
  const float* score_b  = (const float*)d_in[15];
  const int*   n_step   = (const int*)d_in[16];
  float* out = (float*)d_out;

  float* p = (float*)d_ws;
  float* attn_feat = p; p += (size_t)NS*HH;
  float* hop_feat  = p; p += (size_t)NS*HH;
  float* HQT  = p; p += (size_t)HH*NS;
  float* HAT  = p; p += (size_t)HH*NS;
  float* memT = p; p += (size_t)DI*NS;
  float* wqT  = p; p += (size_t)HH*HH;
  float* Ms   = p; p += NS;
  float* xst  = p; p += DI;
  float* hb   = p; p += 2*HH;
  float* qw1  = p; p += HH;
  float* qw2  = p; p += HH;
  float* qw3  = p; p += HH;
  float* w1   = p; p += NS;
  float* w2   = p; p += NS;
  float* w3   = p; p += NS;
  float* s1p  = p; p += NB;
  float* s2p  = p; p += NB;
  float* s3p  = p; p += NB;
  int* bar = (int*)p;
  size_t need = (size_t)((char*)(bar + 64) - (char*)d_ws);
  if (ws_size < need) return;   // workspace too small: bail (will show as wrong output)

  initk<<<1, 64, 0, stream>>>(bar);
  dim3 gg(HH/64, NS/64);
  gemmk<false><<<gg, 256, 0, stream>>>(attn_mem, attn_wm, attn_feat, NS, HH, DI);
  gemmk<false><<<gg, 256, 0, stream>>>(attn_mem, hop_wm,  hop_feat,  NS, HH, DI);
  gemmk<true ><<<gg, 256, 0, stream>>>(hop_feat, hop_wq,  HQT, NS, HH, HH);
  gemmk<true ><<<gg, 256, 0, stream>>>(hop_feat, attn_wq, HAT, NS, HH, HH);
  transpk<<<dim3(DI/32, NS/32), dim3(32,8), 0, stream>>>(attn_mem, memT, NS, DI);
  transpk<<<dim3(HH/32, HH/32), dim3(32,8), 0, stream>>>(hop_wq, wqT, HH, HH);
  msk<<<NS/4, 256, 0, stream>>>(attn_mem, score_w, Ms);

  stepk<<<NB, TPB, 0, stream>>>(attn_feat, hop_feat, HQT, HAT, memT, wqT, Ms,
      xst, hb, qw1, qw2, qw3, w1, w2, w3, s1p, s2p, s3p, bar,
      hop_v, attn_v, init_h, init_c, init_i, w_ih, w_hh, b_ih, b_hh,
      score_b, n_step, out);
}

// Round 2
// 11399.537 us; speedup vs baseline: 1.7184x; 1.7184x over previous
//
#include <hip/hip_runtime.h>

#define NS 4096   // sentences
#define DI 1024   // D_IN
#define HH 1024   // HID
#define NB 256    // persistent blocks
#define TPB 1024  // 16 waves/block
#define LOG2E 1.4426950408889634f

typedef __attribute__((ext_vector_type(8))) unsigned short us8v;

__device__ __forceinline__ float ld_b(const float* p){
  return __hip_atomic_load(p, __ATOMIC_RELAXED, __HIP_MEMORY_SCOPE_AGENT);
}
__device__ __forceinline__ void st_b(float* p, float v){
  __hip_atomic_store(p, v, __ATOMIC_RELAXED, __HIP_MEMORY_SCOPE_AGENT);
}
__device__ __forceinline__ float fexp2f_(float x){ return __builtin_amdgcn_exp2f(x); }
__device__ __forceinline__ float frcpf_(float x){ return __builtin_amdgcn_rcpf(x); }
__device__ __forceinline__ float ftanh_(float x){ float t=fexp2f_(x*(2.f*LOG2E)); return 1.f-2.f*frcpf_(t+1.f); }
__device__ __forceinline__ float fsigm_(float x){ return frcpf_(1.f+fexp2f_(-x*LOG2E)); }
__device__ __forceinline__ float fexpf_(float x){ return fexp2f_(x*LOG2E); }
__device__ __forceinline__ float b2f(unsigned short u){ return __uint_as_float(((unsigned)u)<<16); }
__device__ __forceinline__ unsigned short rne(float f){
  unsigned u = __float_as_uint(f);
  u += 0x7FFFu + ((u>>16)&1u);
  return (unsigned short)(u>>16);
}
__device__ __forceinline__ float red64(float v){
  #pragma unroll
  for (int off=32; off; off>>=1) v += __shfl_xor(v, off, 64);
  return v;
}
__device__ __forceinline__ float dot8(const unsigned short* wp, const float* xp){
  us8v u = *(const us8v*)wp;
  float s = 0.f;
  #pragma unroll
  for (int k=0;k<8;++k) s = fmaf(b2f(u[k]), xp[k], s);
  return s;
}
__device__ __forceinline__ float att8(const unsigned short* fp, const float* qp, const float* vp){
  us8v u = *(const us8v*)fp;
  float s = 0.f;
  #pragma unroll
  for (int k=0;k<8;++k) s = fmaf(ftanh_(b2f(u[k]) + qp[k]), vp[k], s);
  return s;
}

// ---- tree grid barrier: 8 group counters (128B apart) + 1 L2 counter + gen.
// Monotonic counters -> no resets, no reset/release ordering hazard.
__device__ __forceinline__ void gbar(int* bar, int ep){
  __syncthreads();               // drains each wave's vmem before arrival
  if (threadIdx.x == 0){
    asm volatile("s_waitcnt vmcnt(0) lgkmcnt(0)" ::: "memory");
    int* gen = bar + 288;
    int g = blockIdx.x >> 5;     // 8 groups of 32 blocks
    int p1 = __hip_atomic_fetch_add(bar + g*32, 1, __ATOMIC_RELAXED, __HIP_MEMORY_SCOPE_AGENT);
    if ((p1 & 31) == 31){
      int p2 = __hip_atomic_fetch_add(bar + 256, 1, __ATOMIC_RELAXED, __HIP_MEMORY_SCOPE_AGENT);
      if ((p2 & 7) == 7)
        __hip_atomic_store(gen, (p2 >> 3) + 1, __ATOMIC_RELAXED, __HIP_MEMORY_SCOPE_AGENT);
    }
    while (__hip_atomic_load(gen, __ATOMIC_RELAXED, __HIP_MEMORY_SCOPE_AGENT) <= ep)
      __builtin_amdgcn_s_sleep(1);
  }
  __syncthreads();
}

// ---------------- precompute kernels ----------------
__global__ void initk(int* bar){ bar[threadIdx.x] = 0; }   // 512 threads

// C[M,N] = A[M,K] @ B[K,N].
// MODE 0: fp32 C; 1: bf16 CH; 2: bf16 CH transposed [N,M]; 3: fp32 C + bf16 CH
template<int MODE>
__global__ __launch_bounds__(256) void gemmk(const float* __restrict__ A,
                                             const float* __restrict__ B,
                                             float* __restrict__ C,
                                             unsigned short* __restrict__ CH,
                                             int M, int N, int K)
{
  __shared__ float As[64][17];
  __shared__ float Bs[16][68];
  const int tid = threadIdx.x;
  const int tx = tid & 15, ty = tid >> 4;
  const int r0 = blockIdx.y*64, c0 = blockIdx.x*64;
  float acc[4][4] = {};
  for (int k0 = 0; k0 < K; k0 += 16){
    int ar = tid >> 2, aq = tid & 3;
    float4 a4 = *(const float4*)&A[(size_t)(r0+ar)*K + k0 + aq*4];
    As[ar][aq*4+0]=a4.x; As[ar][aq*4+1]=a4.y; As[ar][aq*4+2]=a4.z; As[ar][aq*4+3]=a4.w;
    int br = tid >> 4, bq = tid & 15;
    float4 b4 = *(const float4*)&B[(size_t)(k0+br)*N + c0 + bq*4];
    Bs[br][bq*4+0]=b4.x; Bs[br][bq*4+1]=b4.y; Bs[br][bq*4+2]=b4.z; Bs[br][bq*4+3]=b4.w;
    __syncthreads();
    #pragma unroll
    for (int kk=0; kk<16; ++kk){
      float a0=As[ty*4+0][kk], a1=As[ty*4+1][kk], a2=As[ty*4+2][kk], a3=As[ty*4+3][kk];
      float b0=Bs[kk][tx*4+0], b1=Bs[kk][tx*4+1], b2=Bs[kk][tx*4+2], b3=Bs[kk][tx*4+3];
      acc[0][0]+=a0*b0; acc[0][1]+=a0*b1; acc[0][2]+=a0*b2; acc[0][3]+=a0*b3;
      acc[1][0]+=a1*b0; acc[1][1]+=a1*b1; acc[1][2]+=a1*b2; acc[1][3]+=a1*b3;
      acc[2][0]+=a2*b0; acc[2][1]+=a2*b1; acc[2][2]+=a2*b2; acc[2][3]+=a2*b3;
      acc[3][0]+=a3*b0; acc[3][1]+=a3*b1; acc[3][2]+=a3*b2; acc[3][3]+=a3*b3;
    }
    __syncthreads();
  }
  if constexpr (MODE==0 || MODE==3){
    #pragma unroll
    for (int i=0;i<4;++i){
      float4 o; o.x=acc[i][0]; o.y=acc[i][1]; o.z=acc[i][2]; o.w=acc[i][3];
      *(float4*)&C[(size_t)(r0+ty*4+i)*N + c0 + tx*4] = o;
    }
  }
  if constexpr (MODE==1 || MODE==3){
    #pragma unroll
    for (int i=0;i<4;++i){
      ushort4 o; o.x=rne(acc[i][0]); o.y=rne(acc[i][1]); o.z=rne(acc[i][2]); o.w=rne(acc[i][3]);
      *(ushort4*)&CH[(size_t)(r0+ty*4+i)*N + c0 + tx*4] = o;
    }
  }
  if constexpr (MODE==2){
    __shared__ float Cs[64][65];
    #pragma unroll
    for (int i=0;i<4;++i)
      #pragma unroll
      for (int j=0;j<4;++j) Cs[ty*4+i][tx*4+j] = acc[i][j];
    __syncthreads();
    #pragma unroll
    for (int e=0;e<16;++e){
      int idx = tid + 256*e;
      int cc = idx >> 6, rr = idx & 63;
      CH[(size_t)(c0+cc)*M + r0 + rr] = rne(Cs[rr][cc]);
    }
  }
}

__global__ void transpkH(const float* __restrict__ in, unsigned short* __restrict__ out, int R, int C){
  __shared__ float s[32][33];
  int c0 = blockIdx.x*32, r0 = blockIdx.y*32;
  int x = threadIdx.x, y = threadIdx.y;
  for (int i=0;i<32;i+=8) s[y+i][x] = in[(size_t)(r0+y+i)*C + c0 + x];
  __syncthreads();
  for (int i=0;i<32;i+=8) out[(size_t)(c0+y+i)*R + r0 + x] = rne(s[x][y+i]);
}

__global__ void convk(const float* __restrict__ in, unsigned short* __restrict__ out, int n){
  int i = (blockIdx.x*blockDim.x + threadIdx.x)*4;
  if (i < n){
    float4 f = *(const float4*)&in[i];
    ushort4 o; o.x=rne(f.x); o.y=rne(f.y); o.z=rne(f.z); o.w=rne(f.w);
    *(ushort4*)&out[i] = o;
  }
}

// ---------------- persistent step kernel phases ----------------
// att: wave wv owns row n=16bb+wv: e=sum tanh(F[n]+qw).v -> w=exp(e); block sum -> spart[bb]
__device__ __forceinline__ void att_ph(const unsigned short* __restrict__ FH, const float* vls,
    const float* qwb, float* wout, float* spart,
    int bb, int wv, int ln, int tid, float* qls, float* wred)
{
  qls[tid] = ld_b(&qwb[tid]);
  __syncthreads();
  int n = 16*bb + wv;
  const unsigned short* Fr = FH + (size_t)n*HH;
  float e = 0.f;
  #pragma unroll
  for (int ps=0; ps<2; ++ps){
    int base = ps*512 + ln*8;
    e += att8(Fr+base, &qls[base], &vls[base]);
  }
  e = red64(e);
  if (ln==0){ float w = fexpf_(e); st_b(&wout[n], w); wred[wv] = w; }  // |e|<=sum|v|~45: no overflow
  __syncthreads();
  if (tid==0){
    float s = 0.f;
    #pragma unroll
    for (int r=0;r<16;++r) s += wred[r];
    st_b(&spart[bb], s);
  }
}

// col: dst[4bb+g] = (sum_n w[n]*MT[4bb+g][n]) / sum(spart); wave (g,sub) does 1024-chunk
__device__ __forceinline__ void col_ph(const unsigned short* __restrict__ MT, float* dst,
    const float* wb, const float* spart,
    int bb, int wv, int ln, int tid, float* wls, float* ssp, float* pbuf, float* stot)
{
  #pragma unroll
  for (int i=0;i<4;++i) wls[tid + (i<<10)] = ld_b(&wb[tid + (i<<10)]);
  if (tid < NB) ssp[tid] = ld_b(&spart[tid]);
  __syncthreads();
  int g = wv>>2, sub = wv&3;
  int j = 4*bb + g;
  const unsigned short* row = MT + (size_t)j*NS + (sub<<10);
  const float* wc = &wls[sub<<10];
  float a = 0.f;
  #pragma unroll
  for (int ps=0; ps<2; ++ps){
    int base = ps*512 + ln*8;
    a += dot8(row+base, &wc[base]);
  }
  a = red64(a);
  if (ln==0) pbuf[wv] = a;
  if (wv==0){
    float sp = ssp[ln] + ssp[ln+64] + ssp[ln+128] + ssp[ln+192];
    sp = red64(sp);
    if (ln==0) *stot = sp;
  }
  __syncthreads();
  if (tid < 4){
    float s = pbuf[4*tid]+pbuf[4*tid+1]+pbuf[4*tid+2]+pbuf[4*tid+3];
    st_b(&dst[4*bb+tid], s / *stot);
  }
}

__global__ __launch_bounds__(TPB) void stepk(
  const unsigned short* __restrict__ attn_featH, const unsigned short* __restrict__ hop_featH,
  const unsigned short* __restrict__ HQTH, const unsigned short* __restrict__ HATH,
  const unsigned short* __restrict__ memTH, const unsigned short* __restrict__ wqTH,
  const unsigned short* __restrict__ wihH, const unsigned short* __restrict__ whhH,
  const float* __restrict__ b_ih, const float* __restrict__ b_hh,
  const float* __restrict__ hop_v, const float* __restrict__ attn_v,
  const float* __restrict__ init_h, const float* __restrict__ init_c,
  const float* __restrict__ init_i,
  const float* __restrict__ score_w, const float* __restrict__ score_b,
  const int* __restrict__ n_step,
  float* xst, float* hb, float* qwb, float* wb, float* spart, int* bar,
  float* __restrict__ out)
{
  const int bb = blockIdx.x, tid = threadIdx.x;
  const int wv = tid>>6, ln = tid&63;
  __shared__ float xh[2*HH];
  __shared__ float qls[HH];
  __shared__ float wls[NS];
  __shared__ float ssp[NB];
  __shared__ float vhop[HH], vatt[HH];
  __shared__ float gbuf[16], wred[16], pbuf[16], cl[4];
  __shared__ float stot;
  int ep = 0;

  vhop[tid] = hop_v[tid];
  vatt[tid] = attn_v[tid];
  const int T = *n_step;
  const float sb = score_b[0];
  __syncthreads();

  for (int t=0; t<T; ++t){
    const int hw = (t+1)&1;
    // ---- Ph1: LSTM (wave wv -> gate row R; block owns h/c dims 4bb..4bb+3) ----
    if (t==0){ xh[tid] = init_i[tid]; xh[HH+tid] = init_h[tid]; }
    else     { xh[tid] = ld_b(&xst[tid]); xh[HH+tid] = ld_b(&hb[(t&1)*HH + tid]); }
    __syncthreads();
    {
      const int R = (wv>>2)*HH + 4*bb + (wv&3);
      const unsigned short* wi = wihH + (size_t)R*DI;
      const unsigned short* wh = whhH + (size_t)R*HH;
      float p = 0.f;
      #pragma unroll
      for (int ps=0; ps<2; ++ps){
        int base = ps*512 + ln*8;
        p += dot8(wi+base, &xh[base]);
        p += dot8(wh+base, &xh[HH+base]);
      }
      p = red64(p);
      if (ln==0) gbuf[wv] = p + b_ih[R] + b_hh[R];
    }
    __syncthreads();
    if (tid < 4){
      float ii=fsigm_(gbuf[tid]),   ff=fsigm_(gbuf[4+tid]);
      float gg=ftanh_(gbuf[8+tid]), oo=fsigm_(gbuf[12+tid]);
      float c = (t==0) ? init_c[4*bb+tid] : cl[tid];
      float c2 = ff*c + ii*gg;
      cl[tid] = c2;
      st_b(&hb[(size_t)hw*HH + 4*bb + tid], oo*ftanh_(c2));
    }
    gbar(bar, ep); ++ep;

    // ---- Ph2: qw1 = h @ hop_wq (waves 0-3); score[t-1] (block 0, wave 4) ----
    qls[tid] = ld_b(&hb[(size_t)hw*HH + tid]);
    __syncthreads();
    if (wv < 4){
      int j = 4*bb + wv;
      const unsigned short* row = wqTH + (size_t)j*HH;
      float a = 0.f;
      #pragma unroll
      for (int ps=0; ps<2; ++ps){ int base = ps*512 + ln*8; a += dot8(row+base, &qls[base]); }
      a = red64(a);
      if (ln==0) st_b(&qwb[j], a);
    } else if (wv==4 && bb==0 && t>0){
      float a = 0.f;
      #pragma unroll
      for (int m=0;m<16;++m){ int i = ln + (m<<6); a += ld_b(&xst[i]) * score_w[i]; }
      a = red64(a);
      if (ln==0) out[t-1] = a + sb;
    }
    gbar(bar, ep); ++ep;

    // ---- Ph3: hop attention 1 ----
    att_ph(hop_featH, vhop, qwb, wb, spart, bb, wv, ln, tid, qls, wred);
    gbar(bar, ep); ++ep;
    // ---- Ph4: qw2 = (w1 @ HQ)/s1 ----
    col_ph(HQTH, qwb, wb, spart, bb, wv, ln, tid, wls, ssp, pbuf, &stot);
    gbar(bar, ep); ++ep;
    // ---- Ph5: hop attention 2 ----
    att_ph(hop_featH, vhop, qwb, wb, spart, bb, wv, ln, tid, qls, wred);
    gbar(bar, ep); ++ep;
    // ---- Ph6: qw3 = (w2 @ HA)/s2 ----
    col_ph(HATH, qwb, wb, spart, bb, wv, ln, tid, wls, ssp, pbuf, &stot);
    gbar(bar, ep); ++ep;
    // ---- Ph7: final attention ----
    att_ph(attn_featH, vatt, qwb, wb, spart, bb, wv, ln, tid, qls, wred);
    gbar(bar, ep); ++ep;
    // ---- Ph8: x = (w3 @ mem)/s3 ----
    col_ph(memTH, xst, wb, spart, bb, wv, ln, tid, wls, ssp, pbuf, &stot);
    gbar(bar, ep); ++ep;
  }
  // final score for t = T-1
  if (bb==0 && wv==0 && T>0){
    float a = 0.f;
    #pragma unroll
    for (int m=0;m<16;++m){ int i = ln + (m<<6); a += ld_b(&xst[i]) * score_w[i]; }
    a = red64(a);
    if (ln==0) out[T-1] = a + sb;
  }
}

// ---------------- host launch ----------------
extern "C" void kernel_launch(void* const* d_in, const int* in_sizes, int n_in,
                              void* d_out, int out_size, void* d_ws, size_t ws_size,
                              hipStream_t stream)
{
  (void)in_sizes; (void)n_in; (void)out_size;
  const float* attn_mem = (const float*)d_in[0];
  const float* attn_wm  = (const float*)d_in[1];
  const float* attn_wq  = (const float*)d_in[2];
  const float* attn_v   = (const float*)d_in[3];
  const float* hop_wm   = (const float*)d_in[4];
  const float* hop_wq   = (const float*)d_in[5];
  const float* hop_v    = (const float*)d_in[6];
  const float* init_h   = (const float*)d_in[7];
  const float* init_c   = (const float*)d_in[8];
  const float* init_i   = (const float*)d_in[9];
  const float* w_ih     = (const float*)d_in[10];
  const float* w_hh     = (const float*)d_in[11];
  const float* b_ih     = (const float*)d_in[12];
  const float* b_hh     = (const float*)d_in[13];
  const float* score_w  = (const float*)d_in[14];
  const float* score_b  = (const float*)d_in[15];
  const int*   n_step   = (const int*)d_in[16];
  float* out = (float*)d_out;

  // fp32 region
  float* fp = (float*)d_ws;
  float* hop_feat = fp; fp += (size_t)NS*HH;   // 16.8 MB
  float* xst  = fp; fp += DI;
  float* hb   = fp; fp += 2*HH;
  float* qwb  = fp; fp += HH;
  float* wb   = fp; fp += NS;
  float* spart= fp; fp += NB;
  // bf16 region
  unsigned short* us = (unsigned short*)fp;
  unsigned short* attn_featH = us; us += (size_t)NS*HH;
  unsigned short* hop_featH  = us; us += (size_t)NS*HH;
  unsigned short* HQTH  = us; us += (size_t)HH*NS;
  unsigned short* HATH  = us; us += (size_t)HH*NS;
  unsigned short* memTH = us; us += (size_t)DI*NS;
  unsigned short* wqTH  = us; us += (size_t)HH*HH;
  unsigned short* wihH  = us; us += (size_t)4*HH*DI;
  unsigned short* whhH  = us; us += (size_t)4*HH*HH;
  int* bar = (int*)(us + 256);  // pad + align
  bar = (int*)(((uintptr_t)bar + 511) & ~(uintptr_t)511);
  size_t need = (size_t)((char*)(bar + 512) - (char*)d_ws);
  if (ws_size < need) return;

  initk<<<1, 512, 0, stream>>>(bar);
  convk<<<4096, 256, 0, stream>>>(w_ih, wihH, 4*HH*DI);
  convk<<<4096, 256, 0, stream>>>(w_hh, whhH, 4*HH*HH);
  dim3 gg(HH/64, NS/64);
  gemmk<3><<<gg, 256, 0, stream>>>(attn_mem, hop_wm,  hop_feat, hop_featH, NS, HH, DI);
  gemmk<1><<<gg, 256, 0, stream>>>(attn_mem, attn_wm, nullptr, attn_featH, NS, HH, DI);
  gemmk<2><<<gg, 256, 0, stream>>>(hop_feat, hop_wq,  nullptr, HQTH, NS, HH, HH);
  gemmk<2><<<gg, 256, 0, stream>>>(hop_feat, attn_wq, nullptr, HATH, NS, HH, HH);
  transpkH<<<dim3(DI/32, NS/32), dim3(32,8), 0, stream>>>(attn_mem, memTH, NS, DI);
  transpkH<<<dim3(HH/32, HH/32), dim3(32,8), 0, stream>>>(hop_wq, wqTH, HH, HH);

  stepk<<<NB, TPB, 0, stream>>>(attn_featH, hop_featH, HQTH, HATH, memTH, wqTH,
      wihH, whhH, b_ih, b_hh, hop_v, attn_v, init_h, init_c, init_i,
      score_w, score_b, n_step,
      xst, hb, qwb, wb, spart, bar, out);
}

// Round 3
// 11366.915 us; speedup vs baseline: 1.7233x; 1.0029x over previous
//
#include <hip/hip_runtime.h>

#define NS 4096   // sentences
#define DI 1024   // D_IN
#define HH 1024   // HID
#define NB 256    // persistent blocks
#define TPB 1024  // 16 waves/block
#define LOG2E 1.4426950408889634f

__device__ __forceinline__ float ld_b(const float* p){
  return __hip_atomic_load(p, __ATOMIC_RELAXED, __HIP_MEMORY_SCOPE_AGENT);
}
__device__ __forceinline__ void st_b(float* p, float v){
  __hip_atomic_store(p, v, __ATOMIC_RELAXED, __HIP_MEMORY_SCOPE_AGENT);
}
__device__ __forceinline__ float fexp2f_(float x){ return __builtin_amdgcn_exp2f(x); }
__device__ __forceinline__ float frcpf_(float x){ return __builtin_amdgcn_rcpf(x); }
__device__ __forceinline__ float ftanh_(float x){ float t=fexp2f_(x*(2.f*LOG2E)); return 1.f-2.f*frcpf_(t+1.f); }
__device__ __forceinline__ float fsigm_(float x){ return frcpf_(1.f+fexp2f_(-x*LOG2E)); }
__device__ __forceinline__ float fexpf_(float x){ return fexp2f_(x*LOG2E); }
__device__ __forceinline__ float b2f(unsigned short u){ return __uint_as_float(((unsigned)u)<<16); }
__device__ __forceinline__ unsigned short rne(float f){
  unsigned u = __float_as_uint(f);
  u += 0x7FFFu + ((u>>16)&1u);
  return (unsigned short)(u>>16);
}
__device__ __forceinline__ float red64(float v){
  #pragma unroll
  for (int off=32; off; off>>=1) v += __shfl_xor(v, off, 64);
  return v;
}
// dot of 4 bf16 (regs) with 4 f32
__device__ __forceinline__ float dot4(ushort4 u, float4 x){
  float s = b2f(u.x)*x.x;
  s = fmaf(b2f(u.y), x.y, s);
  s = fmaf(b2f(u.z), x.z, s);
  s = fmaf(b2f(u.w), x.w, s);
  return s;
}
__device__ __forceinline__ float att4(ushort4 u, float4 q, float4 v){
  float s = ftanh_(b2f(u.x)+q.x)*v.x;
  s = fmaf(ftanh_(b2f(u.y)+q.y), v.y, s);
  s = fmaf(ftanh_(b2f(u.z)+q.z), v.z, s);
  s = fmaf(ftanh_(b2f(u.w)+q.w), v.w, s);
  return s;
}

// ---- tree grid barrier: 8 group counters + 1 L2 counter + gen (monotonic) ----
__device__ __forceinline__ void gbar(int* bar, int ep){
  __syncthreads();
  if (threadIdx.x == 0){
    asm volatile("s_waitcnt vmcnt(0) lgkmcnt(0)" ::: "memory");
    int* gen = bar + 288;
    int g = blockIdx.x >> 5;
    int p1 = __hip_atomic_fetch_add(bar + g*32, 1, __ATOMIC_RELAXED, __HIP_MEMORY_SCOPE_AGENT);
    if ((p1 & 31) == 31){
      int p2 = __hip_atomic_fetch_add(bar + 256, 1, __ATOMIC_RELAXED, __HIP_MEMORY_SCOPE_AGENT);
      if ((p2 & 7) == 7)
        __hip_atomic_store(gen, (p2 >> 3) + 1, __ATOMIC_RELAXED, __HIP_MEMORY_SCOPE_AGENT);
    }
    while (__hip_atomic_load(gen, __ATOMIC_RELAXED, __HIP_MEMORY_SCOPE_AGENT) <= ep)
      __builtin_amdgcn_s_sleep(1);
  }
  __syncthreads();
}

// ---------------- precompute kernels ----------------
__global__ void initk(int* bar){ bar[threadIdx.x] = 0; }   // 512 threads

template<int MODE>  // 0: fp32 C; 1: bf16 CH; 2: bf16 CH^T; 3: fp32 C + bf16 CH
__global__ __launch_bounds__(256) void gemmk(const float* __restrict__ A,
                                             const float* __restrict__ B,
                                             float* __restrict__ C,
                                             unsigned short* __restrict__ CH,
                                             int M, int N, int K)
{
  __shared__ float As[64][17];
  __shared__ float Bs[16][68];
  const int tid = threadIdx.x;
  const int tx = tid & 15, ty = tid >> 4;
  const int r0 = blockIdx.y*64, c0 = blockIdx.x*64;
  float acc[4][4] = {};
  for (int k0 = 0; k0 < K; k0 += 16){
    int ar = tid >> 2, aq = tid & 3;
    float4 a4 = *(const float4*)&A[(size_t)(r0+ar)*K + k0 + aq*4];
    As[ar][aq*4+0]=a4.x; As[ar][aq*4+1]=a4.y; As[ar][aq*4+2]=a4.z; As[ar][aq*4+3]=a4.w;
    int br = tid >> 4, bq = tid & 15;
    float4 b4 = *(const float4*)&B[(size_t)(k0+br)*N + c0 + bq*4];
    Bs[br][bq*4+0]=b4.x; Bs[br][bq*4+1]=b4.y; Bs[br][bq*4+2]=b4.z; Bs[br][bq*4+3]=b4.w;
    __syncthreads();
    #pragma unroll
    for (int kk=0; kk<16; ++kk){
      float a0=As[ty*4+0][kk], a1=As[ty*4+1][kk], a2=As[ty*4+2][kk], a3=As[ty*4+3][kk];
      float b0=Bs[kk][tx*4+0], b1=Bs[kk][tx*4+1], b2=Bs[kk][tx*4+2], b3=Bs[kk][tx*4+3];
      acc[0][0]+=a0*b0; acc[0][1]+=a0*b1; acc[0][2]+=a0*b2; acc[0][3]+=a0*b3;
      acc[1][0]+=a1*b0; acc[1][1]+=a1*b1; acc[1][2]+=a1*b2; acc[1][3]+=a1*b3;
      acc[2][0]+=a2*b0; acc[2][1]+=a2*b1; acc[2][2]+=a2*b2; acc[2][3]+=a2*b3;
      acc[3][0]+=a3*b0; acc[3][1]+=a3*b1; acc[3][2]+=a3*b2; acc[3][3]+=a3*b3;
    }
    __syncthreads();
  }
  if constexpr (MODE==0 || MODE==3){
    #pragma unroll
    for (int i=0;i<4;++i){
      float4 o; o.x=acc[i][0]; o.y=acc[i][1]; o.z=acc[i][2]; o.w=acc[i][3];
      *(float4*)&C[(size_t)(r0+ty*4+i)*N + c0 + tx*4] = o;
    }
  }
  if constexpr (MODE==1 || MODE==3){
    #pragma unroll
    for (int i=0;i<4;++i){
      ushort4 o; o.x=rne(acc[i][0]); o.y=rne(acc[i][1]); o.z=rne(acc[i][2]); o.w=rne(acc[i][3]);
      *(ushort4*)&CH[(size_t)(r0+ty*4+i)*N + c0 + tx*4] = o;
    }
  }
  if constexpr (MODE==2){
    __shared__ float Cs[64][65];
    #pragma unroll
    for (int i=0;i<4;++i)
      #pragma unroll
      for (int j=0;j<4;++j) Cs[ty*4+i][tx*4+j] = acc[i][j];
    __syncthreads();
    #pragma unroll
    for (int e=0;e<16;++e){
      int idx = tid + 256*e;
      int cc = idx >> 6, rr = idx & 63;
      CH[(size_t)(c0+cc)*M + r0 + rr] = rne(Cs[rr][cc]);
    }
  }
}

__global__ void transpkH(const float* __restrict__ in, unsigned short* __restrict__ out, int R, int C){
  __shared__ float s[32][33];
  int c0 = blockIdx.x*32, r0 = blockIdx.y*32;
  int x = threadIdx.x, y = threadIdx.y;
  for (int i=0;i<32;i+=8) s[y+i][x] = in[(size_t)(r0+y+i)*C + c0 + x];
  __syncthreads();
  for (int i=0;i<32;i+=8) out[(size_t)(c0+y+i)*R + r0 + x] = rne(s[x][y+i]);
}

__global__ void convk(const float* __restrict__ in, unsigned short* __restrict__ out, int n){
  int i = (blockIdx.x*blockDim.x + threadIdx.x)*4;
  if (i < n){
    float4 f = *(const float4*)&in[i];
    ushort4 o; o.x=rne(f.x); o.y=rne(f.y); o.z=rne(f.z); o.w=rne(f.w);
    *(ushort4*)&out[i] = o;
  }
}

// ---------------- persistent step kernel ----------------
// All matrix rows this block ever touches are pinned in registers:
//   wave wv: att row n=16bb+wv (hop_feat, attn_feat), gate row R=(wv>>2)*HH+4bb+(wv&3),
//   col row j=4bb+(wv>>2) chunk (wv&3) of HQT/HAT/memT/wqT.
// Element<->lane mapping everywhere: el = [chunk]*256 + ln*4 + k (16B/lane: LDS conflict-free).
__global__ __launch_bounds__(TPB) void stepk(
  const unsigned short* __restrict__ attn_featH, const unsigned short* __restrict__ hop_featH,
  const unsigned short* __restrict__ HQTH, const unsigned short* __restrict__ HATH,
  const unsigned short* __restrict__ memTH, const unsigned short* __restrict__ wqTH,
  const unsigned short* __restrict__ wihH, const unsigned short* __restrict__ whhH,
  const float* __restrict__ b_ih, const float* __restrict__ b_hh,
  const float* __restrict__ hop_v, const float* __restrict__ attn_v,
  const float* __restrict__ init_h, const float* __restrict__ init_c,
  const float* __restrict__ init_i,
  const float* __restrict__ score_w, const float* __restrict__ score_b,
  const int* __restrict__ n_step,
  float* xst, float* hb, float* qwb, float* wb, float* spart, int* bar,
  float* __restrict__ out)
{
  const int bb = blockIdx.x, tid = threadIdx.x;
  const int wv = tid>>6, ln = tid&63;
  const int g = wv>>2, sub = wv&3;
  const int rowA = 16*bb + wv;            // att row
  const int jC   = 4*bb + g;              // col row
  const int R    = g*HH + 4*bb + sub;     // LSTM gate row (g=gate, sub=dim)

  __shared__ float xh[2*HH];              // x | h staging
  __shared__ float qls[HH];
  __shared__ float wls[NS];
  __shared__ float ssp[NB];
  __shared__ float vhop[HH], vatt[HH], swls[HH];
  __shared__ float gbuf[16], wred[16], pbuf[16], cl[4];
  __shared__ float stot;
  int ep = 0;

  // ---- pin matrix data in registers (58 VGPRs of bf16 payload per lane) ----
  ushort4 hopf[4], attnf[4], wihr[4], whhr[4], hqr[4], har[4], mtr[4], wqr;
  #pragma unroll
  for (int ps=0; ps<4; ++ps){
    const int e0 = ps*256 + ln*4;
    hopf[ps]  = *(const ushort4*)&hop_featH [(size_t)rowA*HH + e0];
    attnf[ps] = *(const ushort4*)&attn_featH[(size_t)rowA*HH + e0];
    wihr[ps]  = *(const ushort4*)&wihH[(size_t)R*DI + e0];
    whhr[ps]  = *(const ushort4*)&whhH[(size_t)R*HH + e0];
    hqr[ps]   = *(const ushort4*)&HQTH [(size_t)jC*NS + sub*1024 + e0];
    har[ps]   = *(const ushort4*)&HATH [(size_t)jC*NS + sub*1024 + e0];
    mtr[ps]   = *(const ushort4*)&memTH[(size_t)jC*NS + sub*1024 + e0];
  }
  wqr = *(const ushort4*)&wqTH[(size_t)jC*HH + sub*256 + ln*4];
  const float bR = b_ih[R] + b_hh[R];

  vhop[tid] = hop_v[tid];
  vatt[tid] = attn_v[tid];
  swls[tid] = score_w[tid];
  const int T = *n_step;
  const float sb = score_b[0];
  __syncthreads();

  for (int t=0; t<T; ++t){
    const int hw = (t+1)&1;
    // ---- Ph1: LSTM gates + h update; score[t-1] on block 0 ----
    if (t==0){ xh[tid] = init_i[tid]; xh[HH+tid] = init_h[tid]; }
    else     { xh[tid] = ld_b(&xst[tid]); xh[HH+tid] = ld_b(&hb[(t&1)*HH + tid]); }
    __syncthreads();
    {
      float p = 0.f;
      #pragma unroll
      for (int ps=0; ps<4; ++ps){
        const int e0 = ps*256 + ln*4;
        p += dot4(wihr[ps], *(const float4*)&xh[e0]);
        p += dot4(whhr[ps], *(const float4*)&xh[HH+e0]);
      }
      p = red64(p);
      if (ln==0) gbuf[wv] = p + bR;
    }
    __syncthreads();
    if (bb==0 && wv==0 && t>0){          // score[t-1] = x_t . score_w + b
      float a = 0.f;
      #pragma unroll
      for (int ps=0; ps<4; ++ps){
        const int e0 = ps*256 + ln*4;
        float4 x = *(const float4*)&xh[e0], s = *(const float4*)&swls[e0];
        a += x.x*s.x; a = fmaf(x.y,s.y,a); a = fmaf(x.z,s.z,a); a = fmaf(x.w,s.w,a);
      }
      a = red64(a);
      if (ln==0) out[t-1] = a + sb;
    }
    if (tid < 4){
      float ii=fsigm_(gbuf[tid]),   ff=fsigm_(gbuf[4+tid]);
      float gg=ftanh_(gbuf[8+tid]), oo=fsigm_(gbuf[12+tid]);
      float c = (t==0) ? init_c[4*bb+tid] : cl[tid];
      float c2 = ff*c + ii*gg;
      cl[tid] = c2;
      st_b(&hb[(size_t)hw*HH + 4*bb + tid], oo*ftanh_(c2));
    }
    gbar(bar, ep); ++ep;

    // ---- Ph2: qw1 = h @ hop_wq ----
    qls[tid] = ld_b(&hb[(size_t)hw*HH + tid]);
    __syncthreads();
    {
      float a = dot4(wqr, *(const float4*)&qls[sub*256 + ln*4]);
      a = red64(a);
      if (ln==0) pbuf[wv] = a;
    }
    __syncthreads();
    if (tid < 4)
      st_b(&qwb[4*bb+tid], pbuf[4*tid]+pbuf[4*tid+1]+pbuf[4*tid+2]+pbuf[4*tid+3]);
    gbar(bar, ep); ++ep;

    // ---- Ph3/5/7 att + Ph4/6/8 col ----
    #pragma unroll
    for (int hop=0; hop<3; ++hop){
      // att: e = sum tanh(F[n]+qw).v -> w=exp(e)
      qls[tid] = ld_b(&qwb[tid]);
      __syncthreads();
      {
        float e = 0.f;
        #pragma unroll
        for (int ps=0; ps<4; ++ps){
          const int e0 = ps*256 + ln*4;
          float4 q = *(const float4*)&qls[e0];
          if (hop<2) e += att4(hopf[ps],  q, *(const float4*)&vhop[e0]);
          else       e += att4(attnf[ps], q, *(const float4*)&vatt[e0]);
        }
        e = red64(e);
        if (ln==0){ float w = fexpf_(e); st_b(&wb[rowA], w); wred[wv] = w; }  // |e|<=sum|v|: no overflow
      }
      __syncthreads();
      if (tid==0){
        float s = 0.f;
        #pragma unroll
        for (int r=0;r<16;++r) s += wred[r];
        st_b(&spart[bb], s);
      }
      gbar(bar, ep); ++ep;

      // col: dst[j] = (w . M[j]) / sum(spart)
      wls[tid]      = ld_b(&wb[tid]);
      wls[tid+1024] = ld_b(&wb[tid+1024]);
      wls[tid+2048] = ld_b(&wb[tid+2048]);
      wls[tid+3072] = ld_b(&wb[tid+3072]);
      if (tid < NB) ssp[tid] = ld_b(&spart[tid]);
      __syncthreads();
      {
        float a = 0.f;
        #pragma unroll
        for (int ps=0; ps<4; ++ps){
          const int e0 = sub*1024 + ps*256 + ln*4;
          float4 w4 = *(const float4*)&wls[e0];
          if (hop==0)      a += dot4(hqr[ps], w4);
          else if (hop==1) a += dot4(har[ps], w4);
          else             a += dot4(mtr[ps], w4);
        }
        a = red64(a);
        if (ln==0) pbuf[wv] = a;
      }
      if (wv==0){
        float sp = ssp[ln] + ssp[ln+64] + ssp[ln+128] + ssp[ln+192];
        sp = red64(sp);
        if (ln==0) stot = sp;
      }
      __syncthreads();
      if (tid < 4){
        float s = (pbuf[4*tid]+pbuf[4*tid+1]+pbuf[4*tid+2]+pbuf[4*tid+3]) / stot;
        float* dst = (hop==2) ? xst : qwb;
        st_b(&dst[4*bb+tid], s);
      }
      gbar(bar, ep); ++ep;
    }
  }
  // final score for t = T-1 (x_T sits in xst)
  if (bb==0 && wv==0 && T>0){
    float a = 0.f;
    #pragma unroll
    for (int m=0;m<16;++m){ int i = ln + (m<<6); a = fmaf(ld_b(&xst[i]), swls[i], a); }
    a = red64(a);
    if (ln==0) out[T-1] = a + sb;
  }
}

// ---------------- host launch ----------------
extern "C" void kernel_launch(void* const* d_in, const int* in_sizes, int n_in,
                              void* d_out, int out_size, void* d_ws, size_t ws_size,
                              hipStream_t stream)
{
  (void)in_sizes; (void)n_in; (void)out_size;
  const float* attn_mem = (const float*)d_in[0];
  const float* attn_wm  = (const float*)d_in[1];
  const float* attn_wq  = (const float*)d_in[2];
  const float* attn_v   = (const float*)d_in[3];
  const float* hop_wm   = (const float*)d_in[4];
  const float* hop_wq   = (const float*)d_in[5];
  const float* hop_v    = (const float*)d_in[6];
  const float* init_h   = (const float*)d_in[7];
  const float* init_c   = (const float*)d_in[8];
  const float* init_i   = (const float*)d_in[9];
  const float* w_ih     = (const float*)d_in[10];
  const float* w_hh     = (const float*)d_in[11];
  const float* b_ih     = (const float*)d_in[12];
  const float* b_hh     = (const float*)d_in[13];
  const float* score_w  = (const float*)d_in[14];
  const float* score_b  = (const float*)d_in[15];
  const int*   n_step   = (const int*)d_in[16];
  float* out = (float*)d_out;

  float* fp = (float*)d_ws;
  float* hop_feat = fp; fp += (size_t)NS*HH;
  float* xst  = fp; fp += DI;
  float* hb   = fp; fp += 2*HH;
  float* qwb  = fp; fp += HH;
  float* wb   = fp; fp += NS;
  float* spart= fp; fp += NB;
  unsigned short* us = (unsigned short*)fp;
  unsigned short* attn_featH = us; us += (size_t)NS*HH;
  unsigned short* hop_featH  = us; us += (size_t)NS*HH;
  unsigned short* HQTH  = us; us += (size_t)HH*NS;
  unsigned short* HATH  = us; us += (size_t)HH*NS;
  unsigned short* memTH = us; us += (size_t)DI*NS;
  unsigned short* wqTH  = us; us += (size_t)HH*HH;
  unsigned short* wihH  = us; us += (size_t)4*HH*DI;
  unsigned short* whhH  = us; us += (size_t)4*HH*HH;
  int* bar = (int*)(us + 256);
  bar = (int*)(((uintptr_t)bar + 511) & ~(uintptr_t)511);
  size_t need = (size_t)((char*)(bar + 512) - (char*)d_ws);
  if (ws_size < need) return;

  initk<<<1, 512, 0, stream>>>(bar);
  convk<<<4096, 256, 0, stream>>>(w_ih, wihH, 4*HH*DI);
  convk<<<4096, 256, 0, stream>>>(w_hh, whhH, 4*HH*HH);
  dim3 gg(HH/64, NS/64);
  gemmk<3><<<gg, 256, 0, stream>>>(attn_mem, hop_wm,  hop_feat, hop_featH, NS, HH, DI);
  gemmk<1><<<gg, 256, 0, stream>>>(attn_mem, attn_wm, nullptr, attn_featH, NS, HH, DI);
  gemmk<2><<<gg, 256, 0, stream>>>(hop_feat, hop_wq,  nullptr, HQTH, NS, HH, HH);
  gemmk<2><<<gg, 256, 0, stream>>>(hop_feat, attn_wq, nullptr, HATH, NS, HH, HH);
  transpkH<<<dim3(DI/32, NS/32), dim3(32,8), 0, stream>>>(attn_mem, memTH, NS, DI);
  transpkH<<<dim3(HH/32, HH/32), dim3(32,8), 0, stream>>>(hop_wq, wqTH, HH, HH);

  stepk<<<NB, TPB, 0, stream>>>(attn_featH, hop_featH, HQTH, HATH, memTH, wqTH,
      wihH, whhH, b_ih, b_hh, hop_v, attn_v, init_h, init_c, init_i,
      score_w, score_b, n_step,
      xst, hb, qwb, wb, spart, bar, out);
}

// Round 4
// 10310.902 us; speedup vs baseline: 1.8998x; 1.1024x over previous
//
#include <hip/hip_runtime.h>

#define NS 4096   // sentences
#define DI 1024   // D_IN
#define HH 1024   // HID
#define NB 256    // persistent blocks
#define TPB 1024  // 16 waves/block
#define LOG2E 1.4426950408889634f

// barrier layout (ints): leaf counters at g*1024 (g<8), mid at 8*1024,
// gen copies at (9+k)*1024 (k<8) -> 17*4KB region
#define BAR_INTS (17*1024)

__device__ __forceinline__ float ld_b(const float* p){
  return __hip_atomic_load(p, __ATOMIC_RELAXED, __HIP_MEMORY_SCOPE_AGENT);
}
__device__ __forceinline__ void st_b(float* p, float v){
  __hip_atomic_store(p, v, __ATOMIC_RELAXED, __HIP_MEMORY_SCOPE_AGENT);
}
__device__ __forceinline__ float fexp2f_(float x){ return __builtin_amdgcn_exp2f(x); }
__device__ __forceinline__ float frcpf_(float x){ return __builtin_amdgcn_rcpf(x); }
__device__ __forceinline__ float ftanh_(float x){ float t=fexp2f_(x*(2.f*LOG2E)); return 1.f-2.f*frcpf_(t+1.f); }
__device__ __forceinline__ float fsigm_(float x){ return frcpf_(1.f+fexp2f_(-x*LOG2E)); }
__device__ __forceinline__ float fexpf_(float x){ return fexp2f_(x*LOG2E); }
__device__ __forceinline__ float b2f(unsigned short u){ return __uint_as_float(((unsigned)u)<<16); }
__device__ __forceinline__ unsigned short rne(float f){
  unsigned u = __float_as_uint(f);
  u += 0x7FFFu + ((u>>16)&1u);
  return (unsigned short)(u>>16);
}
__device__ __forceinline__ float red64(float v){
  #pragma unroll
  for (int off=32; off; off>>=1) v += __shfl_xor(v, off, 64);
  return v;
}
__device__ __forceinline__ float dot4(ushort4 u, float4 x){
  float s = b2f(u.x)*x.x;
  s = fmaf(b2f(u.y), x.y, s);
  s = fmaf(b2f(u.z), x.z, s);
  s = fmaf(b2f(u.w), x.w, s);
  return s;
}
__device__ __forceinline__ float att4(ushort4 u, float4 q, float4 v){
  float s = ftanh_(b2f(u.x)+q.x)*v.x;
  s = fmaf(ftanh_(b2f(u.y)+q.y), v.y, s);
  s = fmaf(ftanh_(b2f(u.z)+q.z), v.z, s);
  s = fmaf(ftanh_(b2f(u.w)+q.w), v.w, s);
  return s;
}

// ---- tree grid barrier: 8 spread leaf counters + mid counter + 8 gen copies ----
__device__ __forceinline__ void gbar(int* bar, int ep){
  __syncthreads();
  if (threadIdx.x == 0){
    asm volatile("s_waitcnt vmcnt(0) lgkmcnt(0)" ::: "memory");
    const int bb = blockIdx.x;
    int p1 = __hip_atomic_fetch_add(bar + (bb>>5)*1024, 1, __ATOMIC_RELAXED, __HIP_MEMORY_SCOPE_AGENT);
    if ((p1 & 31) == 31){
      int p2 = __hip_atomic_fetch_add(bar + 8*1024, 1, __ATOMIC_RELAXED, __HIP_MEMORY_SCOPE_AGENT);
      if ((p2 & 7) == 7){
        int g = (p2 >> 3) + 1;
        #pragma unroll
        for (int k=0;k<8;++k)
          __hip_atomic_store(bar + (9+k)*1024, g, __ATOMIC_RELAXED, __HIP_MEMORY_SCOPE_AGENT);
      }
    }
    int* mygen = bar + (9 + (bb&7))*1024;
    while (__hip_atomic_load(mygen, __ATOMIC_RELAXED, __HIP_MEMORY_SCOPE_AGENT) <= ep)
      __builtin_amdgcn_s_sleep(1);
  }
  __syncthreads();
}

// ---------------- precompute kernels ----------------
__global__ void initk(int* bar){ bar[blockIdx.x*1024 + threadIdx.x] = 0; }  // <<<17,1024>>>

template<int MODE>  // 0: fp32 C; 1: bf16 CH; 2: bf16 CH^T; 3: fp32 C + bf16 CH
__global__ __launch_bounds__(256) void gemmk(const float* __restrict__ A,
                                             const float* __restrict__ B,
                                             float* __restrict__ C,
                                             unsigned short* __restrict__ CH,
                                             int M, int N, int K)
{
  __shared__ float As[64][17];
  __shared__ float Bs[16][68];
  const int tid = threadIdx.x;
  const int tx = tid & 15, ty = tid >> 4;
  const int r0 = blockIdx.y*64, c0 = blockIdx.x*64;
  float acc[4][4] = {};
  for (int k0 = 0; k0 < K; k0 += 16){
    int ar = tid >> 2, aq = tid & 3;
    float4 a4 = *(const float4*)&A[(size_t)(r0+ar)*K + k0 + aq*4];
    As[ar][aq*4+0]=a4.x; As[ar][aq*4+1]=a4.y; As[ar][aq*4+2]=a4.z; As[ar][aq*4+3]=a4.w;
    int br = tid >> 4, bq = tid & 15;
    float4 b4 = *(const float4*)&B[(size_t)(k0+br)*N + c0 + bq*4];
    Bs[br][bq*4+0]=b4.x; Bs[br][bq*4+1]=b4.y; Bs[br][bq*4+2]=b4.z; Bs[br][bq*4+3]=b4.w;
    __syncthreads();
    #pragma unroll
    for (int kk=0; kk<16; ++kk){
      float a0=As[ty*4+0][kk], a1=As[ty*4+1][kk], a2=As[ty*4+2][kk], a3=As[ty*4+3][kk];
      float b0=Bs[kk][tx*4+0], b1=Bs[kk][tx*4+1], b2=Bs[kk][tx*4+2], b3=Bs[kk][tx*4+3];
      acc[0][0]+=a0*b0; acc[0][1]+=a0*b1; acc[0][2]+=a0*b2; acc[0][3]+=a0*b3;
      acc[1][0]+=a1*b0; acc[1][1]+=a1*b1; acc[1][2]+=a1*b2; acc[1][3]+=a1*b3;
      acc[2][0]+=a2*b0; acc[2][1]+=a2*b1; acc[2][2]+=a2*b2; acc[2][3]+=a2*b3;
      acc[3][0]+=a3*b0; acc[3][1]+=a3*b1; acc[3][2]+=a3*b2; acc[3][3]+=a3*b3;
    }
    __syncthreads();
  }
  if constexpr (MODE==0 || MODE==3){
    #pragma unroll
    for (int i=0;i<4;++i){
      float4 o; o.x=acc[i][0]; o.y=acc[i][1]; o.z=acc[i][2]; o.w=acc[i][3];
      *(float4*)&C[(size_t)(r0+ty*4+i)*N + c0 + tx*4] = o;
    }
  }
  if constexpr (MODE==1 || MODE==3){
    #pragma unroll
    for (int i=0;i<4;++i){
      ushort4 o; o.x=rne(acc[i][0]); o.y=rne(acc[i][1]); o.z=rne(acc[i][2]); o.w=rne(acc[i][3]);
      *(ushort4*)&CH[(size_t)(r0+ty*4+i)*N + c0 + tx*4] = o;
    }
  }
  if constexpr (MODE==2){
    __shared__ float Cs[64][65];
    #pragma unroll
    for (int i=0;i<4;++i)
      #pragma unroll
      for (int j=0;j<4;++j) Cs[ty*4+i][tx*4+j] = acc[i][j];
    __syncthreads();
    #pragma unroll
    for (int e=0;e<16;++e){
      int idx = tid + 256*e;
      int cc = idx >> 6, rr = idx & 63;
      CH[(size_t)(c0+cc)*M + r0 + rr] = rne(Cs[rr][cc]);
    }
  }
}

__global__ void transpkH(const float* __restrict__ in, unsigned short* __restrict__ out, int R, int C){
  __shared__ float s[32][33];
  int c0 = blockIdx.x*32, r0 = blockIdx.y*32;
  int x = threadIdx.x, y = threadIdx.y;
  for (int i=0;i<32;i+=8) s[y+i][x] = in[(size_t)(r0+y+i)*C + c0 + x];
  __syncthreads();
  for (int i=0;i<32;i+=8) out[(size_t)(c0+y+i)*R + r0 + x] = rne(s[x][y+i]);
}

__global__ void convk(const float* __restrict__ in, unsigned short* __restrict__ out, int n){
  int i = (blockIdx.x*blockDim.x + threadIdx.x)*4;
  if (i < n){
    float4 f = *(const float4*)&in[i];
    ushort4 o; o.x=rne(f.x); o.y=rne(f.y); o.z=rne(f.z); o.w=rne(f.w);
    *(ushort4*)&out[i] = o;
  }
}

// ---------------- persistent step kernel ----------------
// __launch_bounds__(1024, 4): 16-wave block = 4 waves/EU min -> 128-VGPR budget,
// so the 58 VGPRs of pinned matrix rows stay resident (r3's (1024) default
// capped at 64 and rematerialized the loads every step).
__global__ __launch_bounds__(TPB, 4) void stepk(
  const unsigned short* __restrict__ attn_featH, const unsigned short* __restrict__ hop_featH,
  const unsigned short* __restrict__ HQTH, const unsigned short* __restrict__ HATH,
  const unsigned short* __restrict__ memTH, const unsigned short* __restrict__ wqTH,
  const unsigned short* __restrict__ wihH, const unsigned short* __restrict__ whhH,
  const float* __restrict__ b_ih, const float* __restrict__ b_hh,
  const float* __restrict__ hop_v, const float* __restrict__ attn_v,
  const float* __restrict__ init_h, const float* __restrict__ init_c,
  const float* __restrict__ init_i,
  const float* __restrict__ score_w, const float* __restrict__ score_b,
  const int* __restrict__ n_step,
  float* xst, float* hb, float* qwb, float* wb, int* bar,
  float* __restrict__ out)
{
  const int bb = blockIdx.x, tid = threadIdx.x;
  const int wv = tid>>6, ln = tid&63;
  const int g = wv>>2, sub = wv&3;
  const int rowA = 16*bb + wv;            // att row
  const int jC   = 4*bb + g;              // col row
  const int R    = g*HH + 4*bb + sub;     // LSTM gate row

  __shared__ float xh[2*HH];
  __shared__ float qls[HH];
  __shared__ float wls[NS];
  __shared__ float vhop[HH], vatt[HH], swls[HH];
  __shared__ float gbuf[16], wred[16], pbuf[16], sbuf[16], cl[4];
  int ep = 0;

  // ---- pin matrix rows in registers (58 VGPRs bf16 payload / lane) ----
  ushort4 hopf[4], attnf[4], wihr[4], whhr[4], hqr[4], har[4], mtr[4], wqr;
  #pragma unroll
  for (int ps=0; ps<4; ++ps){
    const int e0 = ps*256 + ln*4;
    hopf[ps]  = *(const ushort4*)&hop_featH [(size_t)rowA*HH + e0];
    attnf[ps] = *(const ushort4*)&attn_featH[(size_t)rowA*HH + e0];
    wihr[ps]  = *(const ushort4*)&wihH[(size_t)R*DI + e0];
    whhr[ps]  = *(const ushort4*)&whhH[(size_t)R*HH + e0];
    hqr[ps]   = *(const ushort4*)&HQTH [(size_t)jC*NS + sub*1024 + e0];
    har[ps]   = *(const ushort4*)&HATH [(size_t)jC*NS + sub*1024 + e0];
    mtr[ps]   = *(const ushort4*)&memTH[(size_t)jC*NS + sub*1024 + e0];
  }
  wqr = *(const ushort4*)&wqTH[(size_t)jC*HH + sub*256 + ln*4];
  const float bR = b_ih[R] + b_hh[R];

  vhop[tid] = hop_v[tid];
  vatt[tid] = attn_v[tid];
  swls[tid] = score_w[tid];
  const int T = *n_step;
  const float sb = score_b[0];
  __syncthreads();

  for (int t=0; t<T; ++t){
    const int hw = (t+1)&1;
    // ---- Ph1: LSTM gates + h update; score[t-1] on block 0 ----
    if (t==0){ xh[tid] = init_i[tid]; xh[HH+tid] = init_h[tid]; }
    else     { xh[tid] = ld_b(&xst[tid]); xh[HH+tid] = ld_b(&hb[(t&1)*HH + tid]); }
    __syncthreads();
    {
      float p = 0.f;
      #pragma unroll
      for (int ps=0; ps<4; ++ps){
        const int e0 = ps*256 + ln*4;
        p += dot4(wihr[ps], *(const float4*)&xh[e0]);
        p += dot4(whhr[ps], *(const float4*)&xh[HH+e0]);
      }
      p = red64(p);
      if (ln==0) gbuf[wv] = p + bR;
    }
    __syncthreads();
    if (bb==0 && wv==0 && t>0){
      float a = 0.f;
      #pragma unroll
      for (int ps=0; ps<4; ++ps){
        const int e0 = ps*256 + ln*4;
        float4 x = *(const float4*)&xh[e0], s = *(const float4*)&swls[e0];
        a += x.x*s.x; a = fmaf(x.y,s.y,a); a = fmaf(x.z,s.z,a); a = fmaf(x.w,s.w,a);
      }
      a = red64(a);
      if (ln==0) out[t-1] = a + sb;
    }
    if (tid < 4){
      float ii=fsigm_(gbuf[tid]),   ff=fsigm_(gbuf[4+tid]);
      float gg=ftanh_(gbuf[8+tid]), oo=fsigm_(gbuf[12+tid]);
      float c = (t==0) ? init_c[4*bb+tid] : cl[tid];
      float c2 = ff*c + ii*gg;
      cl[tid] = c2;
      st_b(&hb[(size_t)hw*HH + 4*bb + tid], oo*ftanh_(c2));
    }
    gbar(bar, ep); ++ep;

    // ---- Ph2: qw1 = h @ hop_wq ----
    qls[tid] = ld_b(&hb[(size_t)hw*HH + tid]);
    __syncthreads();
    {
      float a = dot4(wqr, *(const float4*)&qls[sub*256 + ln*4]);
      a = red64(a);
      if (ln==0) pbuf[wv] = a;
    }
    __syncthreads();
    if (tid < 4)
      st_b(&qwb[4*bb+tid], pbuf[4*tid]+pbuf[4*tid+1]+pbuf[4*tid+2]+pbuf[4*tid+3]);
    gbar(bar, ep); ++ep;

    // ---- 3 hops: att (own row) | col (own 4 dims, denom from LDS) ----
    #pragma unroll
    for (int hop=0; hop<3; ++hop){
      // att: e = sum tanh(F[n]+qw).v -> w=exp(e)
      qls[tid] = ld_b(&qwb[tid]);
      __syncthreads();
      {
        float e = 0.f;
        #pragma unroll
        for (int ps=0; ps<4; ++ps){
          const int e0 = ps*256 + ln*4;
          float4 q = *(const float4*)&qls[e0];
          if (hop<2) e += att4(hopf[ps],  q, *(const float4*)&vhop[e0]);
          else       e += att4(attnf[ps], q, *(const float4*)&vatt[e0]);
        }
        e = red64(e);
        if (ln==0) st_b(&wb[rowA], fexpf_(e));   // |e|<=sum|v|: no overflow
      }
      gbar(bar, ep); ++ep;

      // col: stage all 4096 w in LDS; dot with pinned rows; denom = LDS sum
      wls[tid]      = ld_b(&wb[tid]);
      wls[tid+1024] = ld_b(&wb[tid+1024]);
      wls[tid+2048] = ld_b(&wb[tid+2048]);
      wls[tid+3072] = ld_b(&wb[tid+3072]);
      __syncthreads();
      {
        float a = 0.f;
        #pragma unroll
        for (int ps=0; ps<4; ++ps){
          const int e0 = sub*1024 + ps*256 + ln*4;
          float4 w4 = *(const float4*)&wls[e0];
          if (hop==0)      a += dot4(hqr[ps], w4);
          else if (hop==1) a += dot4(har[ps], w4);
          else             a += dot4(mtr[ps], w4);
        }
        a = red64(a);
        if (ln==0) pbuf[wv] = a;
        // per-wave chunk sum of w for the softmax denominator (local, no LLC)
        float4 sv = *(const float4*)&wls[wv*256 + ln*4];
        float s4 = sv.x + sv.y + sv.z + sv.w;
        s4 = red64(s4);
        if (ln==0) sbuf[wv] = s4;
      }
      __syncthreads();
      if (tid < 4){
        float stot = 0.f;
        #pragma unroll
        for (int k=0;k<16;++k) stot += sbuf[k];
        float s = (pbuf[4*tid]+pbuf[4*tid+1]+pbuf[4*tid+2]+pbuf[4*tid+3]) / stot;
        float* dst = (hop==2) ? xst : qwb;
        st_b(&dst[4*bb+tid], s);
      }
      gbar(bar, ep); ++ep;
    }
  }
  // final score for t = T-1
  if (bb==0 && wv==0 && T>0){
    float a = 0.f;
    #pragma unroll
    for (int m=0;m<16;++m){ int i = ln + (m<<6); a = fmaf(ld_b(&xst[i]), swls[i], a); }
    a = red64(a);
    if (ln==0) out[T-1] = a + sb;
  }
}

// ---------------- host launch ----------------
extern "C" void kernel_launch(void* const* d_in, const int* in_sizes, int n_in,
                              void* d_out, int out_size, void* d_ws, size_t ws_size,
                              hipStream_t stream)
{
  (void)in_sizes; (void)n_in; (void)out_size;
  const float* attn_mem = (const float*)d_in[0];
  const float* attn_wm  = (const float*)d_in[1];
  const float* attn_wq  = (const float*)d_in[2];
  const float* attn_v   = (const float*)d_in[3];
  const float* hop_wm   = (const float*)d_in[4];
  const float* hop_wq   = (const float*)d_in[5];
  const float* hop_v    = (const float*)d_in[6];
  const float* init_h   = (const float*)d_in[7];
  const float* init_c   = (const float*)d_in[8];
  const float* init_i   = (const float*)d_in[9];
  const float* w_ih     = (const float*)d_in[10];
  const float* w_hh     = (const float*)d_in[11];
  const float* b_ih     = (const float*)d_in[12];
  const float* b_hh     = (const float*)d_in[13];
  const float* score_w  = (const float*)d_in[14];
  const float* score_b  = (const float*)d_in[15];
  const int*   n_step   = (const int*)d_in[16];
  float* out = (float*)d_out;

  float* fp = (float*)d_ws;
  float* hop_feat = fp; fp += (size_t)NS*HH;
  float* xst  = fp; fp += DI;
  float* hb   = fp; fp += 2*HH;
  float* qwb  = fp; fp += HH;
  float* wb   = fp; fp += NS;
  unsigned short* us = (unsigned short*)fp;
  unsigned short* attn_featH = us; us += (size_t)NS*HH;
  unsigned short* hop_featH  = us; us += (size_t)NS*HH;
  unsigned short* HQTH  = us; us += (size_t)HH*NS;
  unsigned short* HATH  = us; us += (size_t)HH*NS;
  unsigned short* memTH = us; us += (size_t)DI*NS;
  unsigned short* wqTH  = us; us += (size_t)HH*HH;
  unsigned short* wihH  = us; us += (size_t)4*HH*DI;
  unsigned short* whhH  = us; us += (size_t)4*HH*HH;
  int* bar = (int*)(us + 256);
  bar = (int*)(((uintptr_t)bar + 4095) & ~(uintptr_t)4095);
  size_t need = (size_t)((char*)(bar + BAR_INTS) - (char*)d_ws);
  if (ws_size < need) return;

  initk<<<17, 1024, 0, stream>>>(bar);
  convk<<<4096, 256, 0, stream>>>(w_ih, wihH, 4*HH*DI);
  convk<<<4096, 256, 0, stream>>>(w_hh, whhH, 4*HH*HH);
  dim3 gg(HH/64, NS/64);
  gemmk<3><<<gg, 256, 0, stream>>>(attn_mem, hop_wm,  hop_feat, hop_featH, NS, HH, DI);
  gemmk<1><<<gg, 256, 0, stream>>>(attn_mem, attn_wm, nullptr, attn_featH, NS, HH, DI);
  gemmk<2><<<gg, 256, 0, stream>>>(hop_feat, hop_wq,  nullptr, HQTH, NS, HH, HH);
  gemmk<2><<<gg, 256, 0, stream>>>(hop_feat, attn_wq, nullptr, HATH, NS, HH, HH);
  transpkH<<<dim3(DI/32, NS/32), dim3(32,8), 0, stream>>>(attn_mem, memTH, NS, DI);
  transpkH<<<dim3(HH/32, HH/32), dim3(32,8), 0, stream>>>(hop_wq, wqTH, HH, HH);

  stepk<<<NB, TPB, 0, stream>>>(attn_featH, hop_featH, HQTH, HATH, memTH, wqTH,
      wihH, whhH, b_ih, b_hh, hop_v, attn_v, init_h, init_c, init_i,
      score_w, score_b, n_step,
      xst, hb, qwb, wb, bar, out);
}